// Round 6
// baseline (221.336 us; speedup 1.0000x reference)
//
#include <hip/hip_runtime.h>
#include <hip/hip_bf16.h>
#include <math.h>

// NT-Xent loss, N=4096, D=256. Single persistent fused kernel.
// loss = (1/2N) * sum_i [ 2 + log( sum_{j != i} exp(2*dot_ij - 2) ) - 2*dot(zn_i, zn_pair(i)) ]
// Phase A: normalize rows -> bf16 zn (ws); zero rowtotal + out.   [grid barrier]
// Phase B: 2080 upper-triangular 128x128 MFMA tiles, 4 per block (R2's proven
//          44.9us body): BK=64 x4 single-buffered LDS staging via
//          global_load_lds(16B), XOR-swizzled, fused exp row/col-sum epilogue,
//          pair tiles add -2*pair_dot to out.                     [grid barrier]
// Phase C: loss += sum_i (2 + log(rowtotal[i])) / 2N.
// Grid barriers: device-scope atomic counter + fences (coop-groups pattern);
// 520 blocks, LDS 33.8KB + launch_bounds(256,3) guarantee co-residency (>=3/CU).

using short8  = __attribute__((ext_vector_type(8))) short;
using floatx4 = __attribute__((ext_vector_type(4))) float;

constexpr int TWO_N = 8192;
constexpr int DIM   = 256;
constexpr int GRID  = 520;
constexpr int TPB   = 4;          // tiles per block; 520*4 = 2080 = NTRI
constexpr float INV2N = 1.0f / 8192.0f;

__device__ static inline unsigned short f2bf(float f) {
  unsigned u = __float_as_uint(f);
  return (unsigned short)((u + 0x7fffu + ((u >> 16) & 1u)) >> 16);  // RNE
}

__device__ static inline void async_copy16(const __hip_bfloat16* g, __hip_bfloat16* l) {
  __builtin_amdgcn_global_load_lds(
      (const __attribute__((address_space(1))) void*)(const void*)g,
      (__attribute__((address_space(3))) void*)(void*)l, 16, 0, 0);
}

__device__ static inline void gridbar(unsigned* bar, unsigned target) {
  __syncthreads();
  if (threadIdx.x == 0) {
    __threadfence();  // make my global writes visible (device scope)
    __hip_atomic_fetch_add(bar, 1u, __ATOMIC_ACQ_REL, __HIP_MEMORY_SCOPE_AGENT);
    while (__hip_atomic_load(bar, __ATOMIC_ACQUIRE, __HIP_MEMORY_SCOPE_AGENT) < target)
      __builtin_amdgcn_s_sleep(8);
    __threadfence();  // invalidate so we see others' writes
  }
  __syncthreads();
}

__global__ __launch_bounds__(256, 3) void k_fused(
    const float* __restrict__ zi, const float* __restrict__ zj,
    __hip_bfloat16* __restrict__ zn, float* __restrict__ rowtotal,
    unsigned* __restrict__ bar, float* __restrict__ out)
{
  __shared__ __align__(16) __hip_bfloat16 As[128 * 64];  // 16 KB
  __shared__ __align__(16) __hip_bfloat16 Bs[128 * 64];  // 16 KB
  __shared__ float rowsum[128];
  __shared__ float colsum[128];

  const int tid  = threadIdx.x;
  const int lane = tid & 63;
  const int wave = tid >> 6;

  // ================= Phase A: normalize =================
#pragma unroll
  for (int it = 0; it < 4; ++it) {
    const int row = blockIdx.x * 16 + it * 4 + wave;
    if (row < TWO_N) {
      const float* src = (row < 4096) ? (zi + (size_t)row * DIM)
                                      : (zj + (size_t)(row - 4096) * DIM);
      float4 v = reinterpret_cast<const float4*>(src)[lane];
      float ss = v.x * v.x + v.y * v.y + v.z * v.z + v.w * v.w;
#pragma unroll
      for (int m = 32; m >= 1; m >>= 1) ss += __shfl_xor(ss, m, 64);
      float inv = 1.0f / fmaxf(sqrtf(ss), 1e-8f);
      ushort4 o;
      o.x = f2bf(v.x * inv); o.y = f2bf(v.y * inv);
      o.z = f2bf(v.z * inv); o.w = f2bf(v.w * inv);
      reinterpret_cast<ushort4*>(zn + (size_t)row * DIM)[lane] = o;
    }
  }
  if (blockIdx.x < 32) rowtotal[blockIdx.x * 256 + tid] = 0.0f;
  if (blockIdx.x == 0 && tid == 0) out[0] = 0.0f;

  gridbar(bar, GRID);

  // ================= Phase B: triangular GEMM tiles =================
  const int wm  = wave >> 1;
  const int wn  = wave & 1;
  const int c16 = lane & 15;
  const int q   = lane >> 4;
  const int lane7 = lane & 7;
  const int sub   = lane >> 3;               // 0..7 subrow within 8-row segment
  const int gkoff = ((lane7 ^ sub) << 3);    // swizzled logical 16B slot to fetch

  for (int t = 0; t < TPB; ++t) {
    const int u = blockIdx.x * TPB + t;
    // triangular decode: u -> (ib <= jb)
    int jb = (int)((sqrtf(8.0f * (float)u + 1.0f) - 1.0f) * 0.5f);
    while ((jb + 1) * (jb + 2) / 2 <= u) ++jb;
    while (jb * (jb + 1) / 2 > u) --jb;
    const int ib = u - jb * (jb + 1) / 2;

    const bool diagblk = (ib == jb);
    const bool pairblk = (jb == ib + 32);
    const int i0 = ib * 128;
    const int j0 = jb * 128;

    if (tid < 128) { rowsum[tid] = 0.0f; colsum[tid] = 0.0f; }

    floatx4 acc[4][4] = {};

    // staging bases: waves 0,1 -> As (rows 0..63 / 64..127), waves 2,3 -> Bs
    const __hip_bfloat16* gbase =
        zn + (size_t)((wave < 2 ? i0 : j0) + (wave & 1) * 64) * DIM;
    __hip_bfloat16* lbase = ((wave < 2) ? As : Bs) + (wave & 1) * 64 * 64;

    for (int kk = 0; kk < 4; ++kk) {
      const int k0 = kk * 64;
#pragma unroll
      for (int c = 0; c < 8; ++c) {
        const __hip_bfloat16* gp = gbase + (size_t)(c * 8 + sub) * DIM + k0 + gkoff;
        async_copy16(gp, lbase + c * 512);   // + lane*16B implicit
      }
      __syncthreads();

#pragma unroll
      for (int ks = 0; ks < 2; ++ks) {
        const int phys = (ks * 4 + q) ^ lane7;  // physical 16B slot for this lane
        short8 a[4], b[4];
#pragma unroll
        for (int mt = 0; mt < 4; ++mt)
          a[mt] = *reinterpret_cast<const short8*>(
              As + (wm * 64 + mt * 16 + c16) * 64 + phys * 8);
#pragma unroll
        for (int nt = 0; nt < 4; ++nt)
          b[nt] = *reinterpret_cast<const short8*>(
              Bs + (wn * 64 + nt * 16 + c16) * 64 + phys * 8);
#pragma unroll
        for (int mt = 0; mt < 4; ++mt)
#pragma unroll
          for (int nt = 0; nt < 4; ++nt)
            acc[mt][nt] = __builtin_amdgcn_mfma_f32_16x16x32_bf16(
                a[mt], b[nt], acc[mt][nt], 0, 0, 0);
      }
      __syncthreads();
    }

    // ---- epilogue ----
    // C/D layout: col = c16 (within nt-tile), row = q*4 + reg (within mt-tile).
    float colacc[4] = {0.f, 0.f, 0.f, 0.f};
    float pc = 0.f;
    const bool diagwave = (wm == wn);

#pragma unroll
    for (int mt = 0; mt < 4; ++mt) {
#pragma unroll
      for (int reg = 0; reg < 4; ++reg) {
        const bool onquad = (c16 == q * 4 + reg);  // lane holds subtile-diag elem
        float s = 0.0f;
#pragma unroll
        for (int nt = 0; nt < 4; ++nt) {
          float e = __expf(2.0f * acc[mt][nt][reg] - 2.0f);
          bool skip = diagblk && diagwave && (nt == mt) && onquad;  // self-sim
          s += skip ? 0.0f : e;
          colacc[nt] += e;
        }
        if (pairblk && diagwave && onquad) pc += acc[mt][mt][reg];  // pair dot
        s += __shfl_xor(s, 1, 64);
        s += __shfl_xor(s, 2, 64);
        s += __shfl_xor(s, 4, 64);
        s += __shfl_xor(s, 8, 64);
        if (c16 == 0)
          atomicAdd(&rowsum[wm * 64 + mt * 16 + q * 4 + reg], s);
      }
    }

    if (!diagblk) {
#pragma unroll
      for (int nt = 0; nt < 4; ++nt) {
        float cs = colacc[nt];
        cs += __shfl_xor(cs, 16, 64);
        cs += __shfl_xor(cs, 32, 64);
        if (lane < 16) atomicAdd(&colsum[wn * 64 + nt * 16 + lane], cs);
      }
    }

    if (pairblk && diagwave) {
#pragma unroll
      for (int m = 32; m >= 1; m >>= 1) pc += __shfl_xor(pc, m, 64);
      // pair elem covers rows i and i+4096: each loses 2*dot -> -4*dot total
      if (lane == 0) atomicAdd(out, -4.0f * pc * INV2N);
    }

    __syncthreads();
    if (tid < 128) {
      atomicAdd(&rowtotal[i0 + tid], rowsum[tid]);
      if (!diagblk) atomicAdd(&rowtotal[j0 + tid], colsum[tid]);
    }
  }

  gridbar(bar, 2 * GRID);

  // ================= Phase C: finalize =================
  if (wave == 0) {
    const int row = blockIdx.x * 16 + tid;
    float v = 0.0f;
    if (tid < 16 && row < TWO_N) v = 2.0f + __logf(rowtotal[row]);
    v += __shfl_xor(v, 1, 64);
    v += __shfl_xor(v, 2, 64);
    v += __shfl_xor(v, 4, 64);
    v += __shfl_xor(v, 8, 64);
    if (lane == 0) atomicAdd(out, v * INV2N);
  }
}

// ---------------- launch ----------------
extern "C" void kernel_launch(void* const* d_in, const int* in_sizes, int n_in,
                              void* d_out, int out_size, void* d_ws, size_t ws_size,
                              hipStream_t stream) {
  const float* zi = (const float*)d_in[0];
  const float* zj = (const float*)d_in[1];
  float* out = (float*)d_out;

  __hip_bfloat16* zn = (__hip_bfloat16*)d_ws;                        // 4 MB
  float* rowtotal = (float*)((char*)d_ws + (size_t)TWO_N * DIM * 2); // 32 KB
  unsigned* bar = (unsigned*)((char*)d_ws + (size_t)TWO_N * DIM * 2 + TWO_N * 4);

  hipMemsetAsync(bar, 0, sizeof(unsigned), stream);
  k_fused<<<dim3(GRID), dim3(256), 0, stream>>>(zi, zj, zn, rowtotal, bar, out);
}

// Round 7
// 109.879 us; speedup vs baseline: 2.0144x; 2.0144x over previous
//
#include <hip/hip_runtime.h>
#include <hip/hip_bf16.h>
#include <math.h>

// NT-Xent loss, N=4096, D=256. Triangular MFMA, BK=32 double-buffered LDS,
// atomic-free partial accumulation.
// loss = (1/2N) * sum_i [ 2 + log( sum_{j != i} exp(2*dot_ij - 2) ) - 2*dot(zn_i, zn_pair(i)) ]
// K1: normalize rows -> bf16 zn in ws; zero out.
// K2: 2080 upper-triangular 128x128 tiles. BK=32, LDS double-buffered: stage(kk+1)
//     issued after the barrier, before compute(kk) -> barrier's vmcnt(0) drains
//     one-iteration-old loads (latency hidden). Fused exp row/col-sum epilogue.
//     Partials: P[r][c] (c=0..63): block (ib,jb) writes rowsum->P[band ib][jb],
//     colsum->P[band jb][ib]; every slot written exactly once (no atomics/init).
// K3: 128 blocks: per row sum 64 coalesced partials, loss += (2+log)/2N.

using short8  = __attribute__((ext_vector_type(8))) short;
using floatx4 = __attribute__((ext_vector_type(4))) float;

constexpr int TWO_N = 8192;
constexpr int DIM   = 256;
constexpr int NB    = 64;                 // 8192/128 tiles per side
constexpr int NTRI  = NB * (NB + 1) / 2;  // 2080
constexpr float INV2N = 1.0f / 8192.0f;

__device__ static inline unsigned short f2bf(float f) {
  unsigned u = __float_as_uint(f);
  return (unsigned short)((u + 0x7fffu + ((u >> 16) & 1u)) >> 16);  // RNE
}

__device__ static inline void async_copy16(const __hip_bfloat16* g, __hip_bfloat16* l) {
  __builtin_amdgcn_global_load_lds(
      (const __attribute__((address_space(1))) void*)(const void*)g,
      (__attribute__((address_space(3))) void*)(void*)l, 16, 0, 0);
}

// ---------------- K1: normalize + cast to bf16 ----------------
__global__ __launch_bounds__(256) void k_normalize(
    const float* __restrict__ zi, const float* __restrict__ zj,
    __hip_bfloat16* __restrict__ zn, float* __restrict__ out)
{
  if (blockIdx.x == 0 && threadIdx.x == 0) out[0] = 0.0f;
  const int lane = threadIdx.x & 63;
  const int wave = threadIdx.x >> 6;
  const int row  = blockIdx.x * 4 + wave;
  const float* src = (row < 4096) ? (zi + (size_t)row * DIM)
                                  : (zj + (size_t)(row - 4096) * DIM);
  float4 v = reinterpret_cast<const float4*>(src)[lane];
  float ss = v.x * v.x + v.y * v.y + v.z * v.z + v.w * v.w;
#pragma unroll
  for (int m = 32; m >= 1; m >>= 1) ss += __shfl_xor(ss, m, 64);
  float inv = 1.0f / fmaxf(sqrtf(ss), 1e-8f);
  ushort4 o;
  o.x = f2bf(v.x * inv); o.y = f2bf(v.y * inv);
  o.z = f2bf(v.z * inv); o.w = f2bf(v.w * inv);
  reinterpret_cast<ushort4*>(zn + (size_t)row * DIM)[lane] = o;
}

// ---------------- K2: dbuf triangular GEMM + fused epilogue ----------------
// LDS buf layout per 128x32 tile: row-major [128][32], 4 x 16B slots per row,
// phys_slot = logical_slot ^ (row & 3)  (bank-spread for ds_read_b128).
__global__ __launch_bounds__(256) void k_simexp(
    const __hip_bfloat16* __restrict__ Z, float* __restrict__ P,
    float* __restrict__ out)
{
  __shared__ __align__(16) __hip_bfloat16 Ab[2][128 * 32];  // 2 x 8 KB
  __shared__ __align__(16) __hip_bfloat16 Bb[2][128 * 32];  // 2 x 8 KB
  __shared__ float rowsum[128];
  __shared__ float colsum[128];

  const int tid  = threadIdx.x;
  const int lane = tid & 63;
  const int wave = tid >> 6;
  const int wm   = wave >> 1;
  const int wn   = wave & 1;
  const int c16  = lane & 15;
  const int q    = lane >> 4;

  // triangular decode: blockIdx.x -> (ib <= jb)
  const int u = blockIdx.x;
  int jb = (int)((sqrtf(8.0f * (float)u + 1.0f) - 1.0f) * 0.5f);
  while ((jb + 1) * (jb + 2) / 2 <= u) ++jb;
  while (jb * (jb + 1) / 2 > u) --jb;
  const int ib = u - jb * (jb + 1) / 2;

  const bool diagblk = (ib == jb);
  const bool pairblk = (jb == ib + 32);
  const int i0 = ib * 128;
  const int j0 = jb * 128;

  if (tid < 128) { rowsum[tid] = 0.0f; colsum[tid] = 0.0f; }

  floatx4 acc[4][4] = {};

  // staging: waves 0,1 -> A rows 0..63/64..127; waves 2,3 -> B same.
  // call c covers 16 rows; lane -> (row = c*16 + lane>>2, phys slot = lane&3);
  // fetch logical slot (lane&3) ^ (row&3), row&3 = (lane>>2)&3.
  const int rloc  = lane >> 2;                       // 0..15 within call
  const int koff  = ((lane & 3) ^ (rloc & 3)) << 3;  // logical k-slot to fetch (elems)
  const __hip_bfloat16* gbase =
      Z + (size_t)((wave < 2 ? i0 : j0) + (wave & 1) * 64) * DIM;
  const int lhalf = (wave & 1) * 64 * 32;

#define STAGE(buf_, k0_)                                                      \
  do {                                                                        \
    __hip_bfloat16* lb = ((wave < 2) ? Ab[buf_] : Bb[buf_]) + lhalf;          \
    _Pragma("unroll") for (int c = 0; c < 4; ++c)                             \
        async_copy16(gbase + (size_t)(c * 16 + rloc) * DIM + (k0_) + koff,    \
                     lb + c * 512);                                           \
  } while (0)

  STAGE(0, 0);
#pragma unroll
  for (int kk = 0; kk < 8; ++kk) {
    const int cur = kk & 1;
    __syncthreads();              // drains loads issued one full iteration ago
    if (kk < 7) STAGE(cur ^ 1, (kk + 1) * 32);

    const int phys = q ^ (c16 & 3);  // physical 16B slot for this lane's frag
    short8 a[4], b[4];
#pragma unroll
    for (int mt = 0; mt < 4; ++mt)
      a[mt] = *reinterpret_cast<const short8*>(
          Ab[cur] + (wm * 64 + mt * 16 + c16) * 32 + phys * 8);
#pragma unroll
    for (int nt = 0; nt < 4; ++nt)
      b[nt] = *reinterpret_cast<const short8*>(
          Bb[cur] + (wn * 64 + nt * 16 + c16) * 32 + phys * 8);
#pragma unroll
    for (int mt = 0; mt < 4; ++mt)
#pragma unroll
      for (int nt = 0; nt < 4; ++nt)
        acc[mt][nt] = __builtin_amdgcn_mfma_f32_16x16x32_bf16(
            a[mt], b[nt], acc[mt][nt], 0, 0, 0);
  }
#undef STAGE

  // ---- epilogue ----
  // C/D layout: col = c16 (within nt-tile), row = q*4 + reg (within mt-tile).
  float colacc[4] = {0.f, 0.f, 0.f, 0.f};
  float pc = 0.f;
  const bool diagwave = (wm == wn);

#pragma unroll
  for (int mt = 0; mt < 4; ++mt) {
#pragma unroll
    for (int reg = 0; reg < 4; ++reg) {
      const bool onquad = (c16 == q * 4 + reg);  // lane holds subtile-diag elem
      float s = 0.0f;
#pragma unroll
      for (int nt = 0; nt < 4; ++nt) {
        float e = __expf(2.0f * acc[mt][nt][reg] - 2.0f);
        bool skip = diagblk && diagwave && (nt == mt) && onquad;  // self-sim
        s += skip ? 0.0f : e;
        colacc[nt] += e;
      }
      if (pairblk && diagwave && onquad) pc += acc[mt][mt][reg];  // pair dot
      s += __shfl_xor(s, 1, 64);
      s += __shfl_xor(s, 2, 64);
      s += __shfl_xor(s, 4, 64);
      s += __shfl_xor(s, 8, 64);
      if (c16 == 0)
        atomicAdd(&rowsum[wm * 64 + mt * 16 + q * 4 + reg], s);
    }
  }

  if (!diagblk) {
#pragma unroll
    for (int nt = 0; nt < 4; ++nt) {
      float cs = colacc[nt];
      cs += __shfl_xor(cs, 16, 64);
      cs += __shfl_xor(cs, 32, 64);
      if (lane < 16) atomicAdd(&colsum[wn * 64 + nt * 16 + lane], cs);
    }
  }

  if (pairblk && diagwave) {
#pragma unroll
    for (int m = 32; m >= 1; m >>= 1) pc += __shfl_xor(pc, m, 64);
    // pair elem covers rows i and i+4096: each loses 2*dot -> -4*dot total
    if (lane == 0) atomicAdd(out, -4.0f * pc * INV2N);
  }

  __syncthreads();
  // partial stores: slot (band<=c ? rowsum of block(band,c) : colsum of block(c,band))
  if (tid < 128) {
    P[(size_t)(i0 + tid) * 64 + jb] = rowsum[tid];
    if (!diagblk) P[(size_t)(j0 + tid) * 64 + ib] = colsum[tid];
  }
}

// ---------------- K3: finalize (coalesced partial sum + logs + reduce) ----------------
__global__ __launch_bounds__(256) void k_finalize(
    const float* __restrict__ P, float* __restrict__ out)
{
  __shared__ float wsum[4];
  const int lane = threadIdx.x & 63;
  const int wave = threadIdx.x >> 6;
  float acc = 0.0f;
#pragma unroll
  for (int it = 0; it < 16; ++it) {
    const int r = blockIdx.x * 64 + it * 4 + wave;
    float s = P[(size_t)r * 64 + lane];
#pragma unroll
    for (int m = 32; m >= 1; m >>= 1) s += __shfl_xor(s, m, 64);
    if (lane == 0) acc += 2.0f + __logf(s);
  }
  if (lane == 0) wsum[wave] = acc;
  __syncthreads();
  if (threadIdx.x == 0)
    atomicAdd(out, (wsum[0] + wsum[1] + wsum[2] + wsum[3]) * INV2N);
}

// ---------------- launch ----------------
extern "C" void kernel_launch(void* const* d_in, const int* in_sizes, int n_in,
                              void* d_out, int out_size, void* d_ws, size_t ws_size,
                              hipStream_t stream) {
  const float* zi = (const float*)d_in[0];
  const float* zj = (const float*)d_in[1];
  float* out = (float*)d_out;

  __hip_bfloat16* zn = (__hip_bfloat16*)d_ws;                 // 8192*256*2 = 4 MB
  float* P = (float*)((char*)d_ws + (size_t)TWO_N * DIM * 2); // 8192*64*4 = 2 MB

  k_normalize<<<dim3(TWO_N / 4), dim3(256), 0, stream>>>(zi, zj, zn, out);
  k_simexp<<<dim3(NTRI), dim3(256), 0, stream>>>(zn, P, out);
  k_finalize<<<dim3(TWO_N / 64), dim3(256), 0, stream>>>(P, out);
}